// Round 2
// baseline (21346.083 us; speedup 1.0000x reference)
//
#include <hip/hip_runtime.h>
#include <math.h>

#define VSZ 50000
#define OOVN 50
#define VE 50050
#define EMB 256
#define HE 512
#define HD 512
#define NB 32
#define SRC 400
#define TDD 30
#define G3 1536   // 3*HE = 3*HD
#define SCAN_WGS 128

__device__ __forceinline__ float sigmf(float x) { return 1.f / (1.f + expf(-x)); }

// out[c*rows + r] = in[r*cols + c]
__global__ __launch_bounds__(256) void transpose_kernel(const float* __restrict__ in,
                                                        float* __restrict__ out,
                                                        int rows, int cols) {
    int idx = blockIdx.x * 256 + threadIdx.x;
    if (idx >= rows * cols) return;
    int r = idx / cols, c = idx % cols;
    out[c * rows + r] = in[idx];
}

// gi[(s*NB+n)*G3 + c] = bih[c] + sum_e embed[ids[n*steps+s]][e] * WihT[e*G3+c]
__global__ __launch_bounds__(256) void gi_kernel(const int* __restrict__ ids,
                                                 const float* __restrict__ embed,
                                                 const float* __restrict__ WihT,
                                                 const float* __restrict__ bih,
                                                 float* __restrict__ gi, int steps) {
    __shared__ float sx[16][EMB];
    __shared__ int stok[16];
    int tid = threadIdx.x;
    int g0 = blockIdx.x * 16;
    if (tid < 16) {
        int row = g0 + tid;
        int s = row / NB, n = row % NB;
        stok[tid] = ids[n * steps + s];
    }
    __syncthreads();
    for (int r = 0; r < 16; ++r) sx[r][tid] = embed[(size_t)stok[r] * EMB + tid];
    __syncthreads();
    int c = blockIdx.y * 256 + tid;
    float b = bih[c];
    float acc[16];
#pragma unroll
    for (int r = 0; r < 16; ++r) acc[r] = b;
    for (int e = 0; e < EMB; e += 4) {
        float w0 = WihT[(size_t)(e + 0) * G3 + c];
        float w1 = WihT[(size_t)(e + 1) * G3 + c];
        float w2 = WihT[(size_t)(e + 2) * G3 + c];
        float w3 = WihT[(size_t)(e + 3) * G3 + c];
#pragma unroll
        for (int r = 0; r < 16; ++r) {
            float4 x4 = *(const float4*)&sx[r][e];
            acc[r] += x4.x * w0 + x4.y * w1 + x4.z * w2 + x4.w * w3;
        }
    }
#pragma unroll
    for (int r = 0; r < 16; ++r) gi[(size_t)(g0 + r) * G3 + c] = acc[r];
}

// ---- persistent bidirectional encoder scan ----
// 128 wgs: wg>>6 = dir, (wg&63)*8 = j0. Weights in LDS once; grid barrier per step.
// LDS strides 516 -> conflict-free ds_read_b128 for both h and w given lane map
// (js = tid&7, n = tid>>3): w bank base 12*js+4*g+k (distinct), h base 4*n+k (distinct).
__global__ __launch_bounds__(256) void enc_scan_kernel(
    const float* __restrict__ giF, const float* __restrict__ giB,
    const float* __restrict__ Whh_f, const float* __restrict__ Whh_b,
    const float* __restrict__ bhh_f, const float* __restrict__ bhh_b,
    float* __restrict__ hbuf,          // [2 parity][2 dir][NB][HE]
    float* __restrict__ enc,           // [NB][SRC][1024]
    unsigned* __restrict__ counter) {
    __shared__ float w_s[24 * 516];    // 24 gate-rows (8 j x 3 gates), stride 516
    __shared__ float h_s[32 * 516];
    int wg = blockIdx.x;
    int dir = wg >> 6;
    int j0 = (wg & 63) * 8;
    const float* gi  = dir ? giB : giF;
    const float* Whh = dir ? Whh_b : Whh_f;
    const float* bhh = dir ? bhh_b : bhh_f;
    int tid = threadIdx.x;

    // stage weight slice: w_s[(js*3+g)*516 + k] = Whh[(g*512 + j0+js)*512 + k]
    for (int i = tid; i < 24 * 128; i += 256) {
        int row = i >> 7;              // js*3+g
        int k4 = (i & 127) << 2;
        int js = row / 3, g = row % 3;
        float4 v = *(const float4*)&Whh[((size_t)(g * 512 + j0 + js)) * 512 + k4];
        *(float4*)&w_s[row * 516 + k4] = v;
    }
    int js = tid & 7, n = tid >> 3;
    int j = j0 + js;
    float bR = bhh[j], bZ = bhh[512 + j], bN = bhh[1024 + j];

    for (int t = 0; t < SRC; ++t) {
        int s = dir ? (SRC - 1 - t) : t;
        const float* hcur = hbuf + ((size_t)((t & 1) * 2 + dir)) * (NB * HE);
        float* hnxt = hbuf + ((size_t)(((t + 1) & 1) * 2 + dir)) * (NB * HE);
        __syncthreads();   // weights ready (t=0) / h_s free for overwrite (t>0)
        for (int i = tid; i < 32 * 128; i += 256) {
            int nn2 = i >> 7, k4 = (i & 127) << 2;
            float4 v = *(const float4*)&hcur[nn2 * 512 + k4];
            *(float4*)&h_s[nn2 * 516 + k4] = v;
        }
        __syncthreads();
        const float* wR = &w_s[(js * 3 + 0) * 516];
        const float* wZ = &w_s[(js * 3 + 1) * 516];
        const float* wN = &w_s[(js * 3 + 2) * 516];
        const float* hp = &h_s[n * 516];
        float aR = bR, aZ = bZ, aN = bN;
#pragma unroll 4
        for (int k = 0; k < 512; k += 4) {
            float4 h4 = *(const float4*)&hp[k];
            float4 r4 = *(const float4*)&wR[k];
            float4 z4 = *(const float4*)&wZ[k];
            float4 n4 = *(const float4*)&wN[k];
            aR += h4.x * r4.x + h4.y * r4.y + h4.z * r4.z + h4.w * r4.w;
            aZ += h4.x * z4.x + h4.y * z4.y + h4.z * z4.z + h4.w * z4.w;
            aN += h4.x * n4.x + h4.y * n4.y + h4.z * n4.z + h4.w * n4.w;
        }
        const float* gir = gi + ((size_t)(s * NB + n)) * G3;
        float r  = sigmf(gir[j] + aR);
        float zz = sigmf(gir[512 + j] + aZ);
        float nn = tanhf(gir[1024 + j] + r * aN);
        float hprev = hp[j];
        float h = (1.f - zz) * nn + zz * hprev;
        hnxt[n * 512 + j] = h;
        enc[((size_t)n * SRC + s) * 1024 + dir * 512 + j] = h;
        // grid barrier (all 128 wgs co-resident: 1 wg/CU by LDS, 256 CUs)
        __syncthreads();
        if (tid == 0) {
            __threadfence();
            __hip_atomic_fetch_add(counter, 1u, __ATOMIC_RELEASE, __HIP_MEMORY_SCOPE_AGENT);
            unsigned target = (unsigned)SCAN_WGS * (t + 1);
            while (__hip_atomic_load(counter, __ATOMIC_ACQUIRE, __HIP_MEMORY_SCOPE_AGENT) < target)
                __builtin_amdgcn_s_sleep(2);
        }
        __syncthreads();
    }
}

// Decoder GRU step. grid (16,4), block 256 = 8n x 32j
__global__ __launch_bounds__(256) void dec_step_kernel(
    const float* __restrict__ gi, const float* __restrict__ WhhT,
    const float* __restrict__ bhh, const float* __restrict__ hin,
    float* __restrict__ hout, int t) {
    __shared__ float sh[8][HD];
    int tid = threadIdx.x;
    int n0 = blockIdx.y * 8;
    for (int i = tid; i < 8 * HD; i += 256)
        sh[i >> 9][i & 511] = hin[(size_t)(n0 + (i >> 9)) * HD + (i & 511)];
    __syncthreads();
    int j = blockIdx.x * 32 + (tid & 31);
    int nl = tid >> 5;
    int n = n0 + nl;
    float aR = bhh[j], aZ = bhh[HD + j], aN = bhh[2 * HD + j];
    for (int k = 0; k < HD; k += 4) {
        float4 h4 = *(const float4*)&sh[nl][k];
        const float* w0 = WhhT + (size_t)(k + 0) * G3;
        const float* w1 = WhhT + (size_t)(k + 1) * G3;
        const float* w2 = WhhT + (size_t)(k + 2) * G3;
        const float* w3 = WhhT + (size_t)(k + 3) * G3;
        aR += h4.x * w0[j] + h4.y * w1[j] + h4.z * w2[j] + h4.w * w3[j];
        aZ += h4.x * w0[HD + j] + h4.y * w1[HD + j] + h4.z * w2[HD + j] + h4.w * w3[HD + j];
        aN += h4.x * w0[2 * HD + j] + h4.y * w1[2 * HD + j] + h4.z * w2[2 * HD + j] + h4.w * w3[2 * HD + j];
    }
    const float* gir = gi + (size_t)(t * NB + n) * G3;
    float r  = sigmf(gir[j] + aR);
    float zz = sigmf(gir[HD + j] + aZ);
    float nn = tanhf(gir[2 * HD + j] + r * aN);
    float hp = sh[nl][j];
    hout[(size_t)n * HD + j] = (1.f - zz) * nn + zz * hp;
}

// key_proj: kp[(n*SRC+s)*512 + c] = sum_k enc[row][k]*Wk[k*512+c]. 8 rows/block.
__global__ __launch_bounds__(256) void keyproj_kernel(const float* __restrict__ enc,
                                                      const float* __restrict__ Wk,
                                                      float* __restrict__ kp) {
    __shared__ float sx[8][1024];
    int tid = threadIdx.x;
    int g0 = blockIdx.x * 8;
    for (int i = tid; i < 8 * 1024; i += 256)
        sx[i >> 10][i & 1023] = enc[(size_t)(g0 + (i >> 10)) * 1024 + (i & 1023)];
    __syncthreads();
    int c = blockIdx.y * 256 + tid;
    float acc[8];
#pragma unroll
    for (int r = 0; r < 8; ++r) acc[r] = 0.f;
    for (int k = 0; k < 1024; k += 4) {
        float w0 = Wk[(size_t)(k + 0) * 512 + c];
        float w1 = Wk[(size_t)(k + 1) * 512 + c];
        float w2 = Wk[(size_t)(k + 2) * 512 + c];
        float w3 = Wk[(size_t)(k + 3) * 512 + c];
#pragma unroll
        for (int r = 0; r < 8; ++r) {
            float4 x4 = *(const float4*)&sx[r][k];
            acc[r] += x4.x * w0 + x4.y * w1 + x4.z * w2 + x4.w * w3;
        }
    }
#pragma unroll
    for (int r = 0; r < 8; ++r) kp[(size_t)(g0 + r) * 512 + c] = acc[r];
}

// q[n][j] = battn[j] + sum_k h[n][k]*Wd[k*512+j]; block per n
__global__ __launch_bounds__(256) void q_kernel(const float* __restrict__ h,
                                                const float* __restrict__ Wd,
                                                const float* __restrict__ battn,
                                                float* __restrict__ q) {
    __shared__ float shh[512];
    int n = blockIdx.x, tid = threadIdx.x;
    shh[tid] = h[(size_t)n * 512 + tid];
    shh[256 + tid] = h[(size_t)n * 512 + 256 + tid];
    __syncthreads();
    float a0 = battn[tid], a1 = battn[256 + tid];
    for (int k = 0; k < 512; k += 4) {
        float4 h4 = *(const float4*)&shh[k];
        a0 += h4.x * Wd[(size_t)k * 512 + tid] + h4.y * Wd[(size_t)(k + 1) * 512 + tid]
            + h4.z * Wd[(size_t)(k + 2) * 512 + tid] + h4.w * Wd[(size_t)(k + 3) * 512 + tid];
        a1 += h4.x * Wd[(size_t)k * 512 + 256 + tid] + h4.y * Wd[(size_t)(k + 1) * 512 + 256 + tid]
            + h4.z * Wd[(size_t)(k + 2) * 512 + 256 + tid] + h4.w * Wd[(size_t)(k + 3) * 512 + 256 + tid];
    }
    q[(size_t)n * 512 + tid] = a0;
    q[(size_t)n * 512 + 256 + tid] = a1;
}

// fused escore + softmax over S; block per n, 512 threads (8 waves)
__global__ __launch_bounds__(512) void attn_kernel(const float* __restrict__ kp,
                                                   const float* __restrict__ q,
                                                   const float* __restrict__ vvec,
                                                   const float* __restrict__ mask,
                                                   float* __restrict__ attnw) {
    __shared__ float se[SRC];
    __shared__ float rbuf[512];
    int n = blockIdx.x, tid = threadIdx.x;
    int w = tid >> 6, lane = tid & 63;
    float vreg[8], qreg[8];
#pragma unroll
    for (int i = 0; i < 8; ++i) {
        int d = lane + i * 64;
        vreg[i] = vvec[d];
        qreg[i] = q[(size_t)n * 512 + d];
    }
    for (int s = w; s < SRC; s += 8) {
        const float* kpr = kp + ((size_t)n * SRC + s) * 512;
        float acc = 0.f;
#pragma unroll
        for (int i = 0; i < 8; ++i)
            acc += vreg[i] * tanhf(kpr[lane + i * 64] + qreg[i]);
        for (int off = 32; off; off >>= 1) acc += __shfl_down(acc, off, 64);
        if (lane == 0) se[s] = acc + (1.f - mask[n * SRC + s]) * (-1e10f);
    }
    __syncthreads();
    rbuf[tid] = (tid < SRC) ? se[tid] : -3.4e38f;
    __syncthreads();
    for (int off = 256; off; off >>= 1) { if (tid < off) rbuf[tid] = fmaxf(rbuf[tid], rbuf[tid + off]); __syncthreads(); }
    float m = rbuf[0]; __syncthreads();
    float ex = (tid < SRC) ? expf(se[tid] - m) : 0.f;
    rbuf[tid] = ex; __syncthreads();
    for (int off = 256; off; off >>= 1) { if (tid < off) rbuf[tid] += rbuf[tid + off]; __syncthreads(); }
    float inv = 1.f / rbuf[0];
    if (tid < SRC) attnw[n * SRC + tid] = ex * inv;
}

// ctx[n][d] = sum_s attn[n][s]*enc[n][s][d]; grid (32 n, 4 dchunks)
__global__ __launch_bounds__(256) void ctx_kernel(const float* __restrict__ attnw,
                                                  const float* __restrict__ enc,
                                                  float* __restrict__ ctx) {
    __shared__ float sa[SRC];
    int n = blockIdx.x, tid = threadIdx.x;
    for (int s = tid; s < SRC; s += 256) sa[s] = attnw[n * SRC + s];
    __syncthreads();
    int d = blockIdx.y * 256 + tid;
    const float* er = enc + (size_t)n * SRC * 1024 + d;
    float acc = 0.f;
    for (int s = 0; s < SRC; ++s) acc += sa[s] * er[(size_t)s * 1024];
    ctx[(size_t)n * 1024 + d] = acc;
}

// p_gen[n] = sigmoid([xi, ctx, h] . Wp + bp); block per n
__global__ __launch_bounds__(256) void pgen_kernel(const int* __restrict__ trg_ids,
                                                   const float* __restrict__ embed,
                                                   const float* __restrict__ ctx,
                                                   const float* __restrict__ h,
                                                   const float* __restrict__ Wp,
                                                   const float* __restrict__ bp,
                                                   float* __restrict__ pgen, int t) {
    __shared__ float red[256];
    int n = blockIdx.x, tid = threadIdx.x;
    int tok = trg_ids[n * TDD + t];
    float acc = 0.f;
    for (int i = tid; i < 1792; i += 256) {
        float val;
        if (i < 256) val = embed[(size_t)tok * EMB + i];
        else if (i < 1280) val = ctx[(size_t)n * 1024 + (i - 256)];
        else val = h[(size_t)n * 512 + (i - 1280)];
        acc += val * Wp[i];
    }
    red[tid] = acc; __syncthreads();
    for (int off = 128; off; off >>= 1) { if (tid < off) red[tid] += red[tid + off]; __syncthreads(); }
    if (tid == 0) pgen[n] = 1.f / (1.f + expf(-(red[0] + bp[0])));
}

// hid1[n][j] = b1[j] + [h,ctx] . W1[:,j]; block per n
__global__ __launch_bounds__(256) void hid1_kernel(const float* __restrict__ h,
                                                   const float* __restrict__ ctx,
                                                   const float* __restrict__ W1,
                                                   const float* __restrict__ b1,
                                                   float* __restrict__ hid1) {
    __shared__ float sc[1536];
    int n = blockIdx.x, tid = threadIdx.x;
    for (int i = tid; i < 512; i += 256) sc[i] = h[(size_t)n * 512 + i];
    for (int i = tid; i < 1024; i += 256) sc[512 + i] = ctx[(size_t)n * 1024 + i];
    __syncthreads();
    float a0 = b1[tid], a1 = b1[256 + tid];
    for (int k = 0; k < 1536; k += 4) {
        float4 c4 = *(const float4*)&sc[k];
        a0 += c4.x * W1[(size_t)k * 512 + tid] + c4.y * W1[(size_t)(k + 1) * 512 + tid]
            + c4.z * W1[(size_t)(k + 2) * 512 + tid] + c4.w * W1[(size_t)(k + 3) * 512 + tid];
        a1 += c4.x * W1[(size_t)k * 512 + 256 + tid] + c4.y * W1[(size_t)(k + 1) * 512 + 256 + tid]
            + c4.z * W1[(size_t)(k + 2) * 512 + 256 + tid] + c4.w * W1[(size_t)(k + 3) * 512 + 256 + tid];
    }
    hid1[(size_t)n * 512 + tid] = a0;
    hid1[(size_t)n * 512 + 256 + tid] = a1;
}

// logits[n][j] = b2[j] + hid1[n] . W2[:,j]; thread per j, all 32 n in registers
__global__ __launch_bounds__(256) void logits_kernel(const float* __restrict__ hid1,
                                                     const float* __restrict__ W2,
                                                     const float* __restrict__ b2,
                                                     float* __restrict__ logits) {
    __shared__ float sh[NB][512];   // 64 KB
    int tid = threadIdx.x;
    for (int i = tid; i < NB * 512; i += 256) sh[i >> 9][i & 511] = hid1[i];
    __syncthreads();
    int j = blockIdx.x * 256 + tid;
    if (j >= VSZ) return;
    float acc[NB];
#pragma unroll
    for (int n = 0; n < NB; ++n) acc[n] = 0.f;
    for (int k = 0; k < 512; k += 4) {
        float w0 = W2[(size_t)(k + 0) * VSZ + j];
        float w1 = W2[(size_t)(k + 1) * VSZ + j];
        float w2 = W2[(size_t)(k + 2) * VSZ + j];
        float w3 = W2[(size_t)(k + 3) * VSZ + j];
#pragma unroll
        for (int n = 0; n < NB; ++n) {
            float4 h4 = *(const float4*)&sh[n][k];
            acc[n] += h4.x * w0 + h4.y * w1 + h4.z * w2 + h4.w * w3;
        }
    }
    float bb = b2[j];
#pragma unroll
    for (int n = 0; n < NB; ++n) logits[(size_t)n * VSZ + j] = acc[n] + bb;
}

// softmax over V (exp cached in logits scratch), scale by p_gen, write row, then
// fused pointer-scatter into own row. block per n.
__global__ __launch_bounds__(1024) void out_kernel(float* __restrict__ logits,
                                                   const float* __restrict__ pgen,
                                                   const float* __restrict__ attnw,
                                                   const int* __restrict__ ptr,
                                                   float* __restrict__ out, int t) {
    __shared__ float red[1024];
    int n = blockIdx.x, tid = threadIdx.x;
    float* lrow = logits + (size_t)n * VSZ;
    float m = -3.4e38f;
    for (int j = tid; j < VSZ; j += 1024) m = fmaxf(m, lrow[j]);
    red[tid] = m; __syncthreads();
    for (int off = 512; off; off >>= 1) { if (tid < off) red[tid] = fmaxf(red[tid], red[tid + off]); __syncthreads(); }
    m = red[0]; __syncthreads();
    float sum = 0.f;
    for (int j = tid; j < VSZ; j += 1024) { float e = expf(lrow[j] - m); sum += e; lrow[j] = e; }
    red[tid] = sum; __syncthreads();
    for (int off = 512; off; off >>= 1) { if (tid < off) red[tid] += red[tid + off]; __syncthreads(); }
    float pg = pgen[n];
    float inv = pg / red[0];
    float* orow = out + (size_t)(n * TDD + t) * VE;
    for (int j = tid; j < VE; j += 1024) orow[j] = (j < VSZ) ? lrow[j] * inv : 0.f;
    __syncthreads();
    float cp = 1.f - pg;
    for (int s = tid; s < SRC; s += 1024)
        atomicAdd(&orow[ptr[n * SRC + s]], cp * attnw[n * SRC + s]);
}

extern "C" void kernel_launch(void* const* d_in, const int* in_sizes, int n_in,
                              void* d_out, int out_size, void* d_ws, size_t ws_size,
                              hipStream_t stream) {
    const int*   src_ids  = (const int*)d_in[0];
    const float* src_mask = (const float*)d_in[1];
    const int*   trg_ids  = (const int*)d_in[2];
    const int*   ptr_idx  = (const int*)d_in[3];
    const float* embed    = (const float*)d_in[4];
    const float* Wih_f = (const float*)d_in[5];
    const float* Whh_f = (const float*)d_in[6];
    const float* bih_f = (const float*)d_in[7];
    const float* bhh_f = (const float*)d_in[8];
    const float* Wih_b = (const float*)d_in[9];
    const float* Whh_b = (const float*)d_in[10];
    const float* bih_b = (const float*)d_in[11];
    const float* bhh_b = (const float*)d_in[12];
    const float* Wih_d = (const float*)d_in[13];
    const float* Whh_d = (const float*)d_in[14];
    const float* bih_d = (const float*)d_in[15];
    const float* bhh_d = (const float*)d_in[16];
    const float* Wk    = (const float*)d_in[17];
    const float* Wd    = (const float*)d_in[18];
    const float* battn = (const float*)d_in[19];
    const float* vvec  = (const float*)d_in[20];
    const float* W1    = (const float*)d_in[21];
    const float* b1    = (const float*)d_in[22];
    const float* W2    = (const float*)d_in[23];
    const float* b2    = (const float*)d_in[24];
    const float* Wp    = (const float*)d_in[25];
    const float* bp    = (const float*)d_in[26];
    float* out = (float*)d_out;

    float* w = (float*)d_ws;
    unsigned* counter = (unsigned*)w; w += 64;
    float* WihTf = w; w += 256 * G3;
    float* WihTb = w; w += 256 * G3;
    float* WihTd = w; w += 256 * G3;
    float* WhhTd = w; w += 512 * G3;
    float* giF = w; w += (size_t)SRC * NB * G3;
    float* giB = w; w += (size_t)SRC * NB * G3;
    float* giD = w; w += (size_t)TDD * NB * G3;
    float* enc = w; w += (size_t)NB * SRC * 1024;
    float* kp  = w; w += (size_t)NB * SRC * 512;
    float* hbuf = w; w += 2 * 2 * NB * HE;     // [parity][dir][NB][HE]
    float* hDbuf[2]; hDbuf[0] = w; w += NB * HD; hDbuf[1] = w; w += NB * HD;
    float* q    = w; w += NB * 512;
    float* attnw = w; w += NB * SRC;
    float* ctx  = w; w += NB * 1024;
    float* hid1 = w; w += NB * 512;
    float* pgen = w; w += 64;
    float* logits = w; w += (size_t)NB * VSZ;

    hipMemsetAsync(counter, 0, 64 * sizeof(float), stream);
    hipMemsetAsync(hbuf, 0, 2 * 2 * NB * HE * sizeof(float), stream);
    hipMemsetAsync(hDbuf[0], 0, NB * HD * sizeof(float), stream);

    // ---- weight transposes (Wih for gi kernels; Whh_d for dec_step) ----
    transpose_kernel<<<(G3 * 256 + 255) / 256, 256, 0, stream>>>(Wih_f, WihTf, G3, 256);
    transpose_kernel<<<(G3 * 256 + 255) / 256, 256, 0, stream>>>(Wih_b, WihTb, G3, 256);
    transpose_kernel<<<(G3 * 256 + 255) / 256, 256, 0, stream>>>(Wih_d, WihTd, G3, 256);
    transpose_kernel<<<(G3 * 512 + 255) / 256, 256, 0, stream>>>(Whh_d, WhhTd, G3, 512);

    // ---- input-gate precompute ----
    gi_kernel<<<dim3(SRC * NB / 16, 6), 256, 0, stream>>>(src_ids, embed, WihTf, bih_f, giF, SRC);
    gi_kernel<<<dim3(SRC * NB / 16, 6), 256, 0, stream>>>(src_ids, embed, WihTb, bih_b, giB, SRC);
    gi_kernel<<<dim3(TDD * NB / 16, 6), 256, 0, stream>>>(trg_ids, embed, WihTd, bih_d, giD, TDD);

    // ---- persistent encoder scan (single launch, 400 internal grid barriers) ----
    enc_scan_kernel<<<SCAN_WGS, 256, 0, stream>>>(giF, giB, Whh_f, Whh_b, bhh_f, bhh_b,
                                                  hbuf, enc, counter);

    keyproj_kernel<<<dim3(NB * SRC / 8, 2), 256, 0, stream>>>(enc, Wk, kp);

    // ---- decoder ----
    for (int t = 0; t < TDD; ++t) {
        const float* hi = hDbuf[t & 1];
        float* ho = hDbuf[(t + 1) & 1];
        dec_step_kernel<<<dim3(16, 4), 256, 0, stream>>>(giD, WhhTd, bhh_d, hi, ho, t);
        q_kernel<<<NB, 256, 0, stream>>>(ho, Wd, battn, q);
        attn_kernel<<<NB, 512, 0, stream>>>(kp, q, vvec, src_mask, attnw);
        ctx_kernel<<<dim3(NB, 4), 256, 0, stream>>>(attnw, enc, ctx);
        pgen_kernel<<<NB, 256, 0, stream>>>(trg_ids, embed, ctx, ho, Wp, bp, pgen, t);
        hid1_kernel<<<NB, 256, 0, stream>>>(ho, ctx, W1, b1, hid1);
        logits_kernel<<<(VSZ + 255) / 256, 256, 0, stream>>>(hid1, W2, b2, logits);
        out_kernel<<<NB, 1024, 0, stream>>>(logits, pgen, attnw, ptr_idx, out, t);
    }
}